// Round 8
// baseline (113.177 us; speedup 1.0000x reference)
//
#include <hip/hip_runtime.h>
#include <hip/hip_cooperative_groups.h>
#include <cstddef>
#include <cstdint>

namespace cg = cooperative_groups;

typedef __attribute__((ext_vector_type(8))) _Float16 f16x8;
typedef __attribute__((ext_vector_type(4))) float f32x4;

constexpr int S = 128;
constexpr int H = 64;
constexpr int A = 8;
constexpr float GAMMA = 0.98f;
constexpr float EPS_CLIP = 0.1f;

__device__ __forceinline__ float swishf(float x) {
    return x * __builtin_amdgcn_rcpf(1.0f + __expf(-x));
}
__device__ __forceinline__ f32x4 mfmaf(f16x8 a, f16x8 b, f32x4 c) {
    return __builtin_amdgcn_mfma_f32_16x16x32_f16(a, b, c, 0, 0, 0);
}

// ===== r4 fwd, byte-identical (best measured: bench 62.7 us) =====
// Grid = 2*nbf blocks of 512 threads (8 waves). Blocks [0,nbf): pass 0 over s
// (writes v_s and pi_a). Blocks [nbf,2nbf): pass 1 over s' (writes v_sp).
// 512-thread blocks: weights staged once per 512 rows; LDS 49.5 KB.
// __launch_bounds__(512,2): no register strangling (r3's (512,6) spilled).
// Each wave owns 64 rows as 2 double-tiles of 32 rows; both 16-row tiles of a
// double-tile share every weight-fragment ds_read.
// A-frag (16x32 f16): lane l holds A[l&15][(l>>4)*8 + j].
// B-frag: lane l holds B[(l>>4)*8 + j][l&15].  C/D: col=lane&15, row=(lane>>4)*4+reg.
__global__ __launch_bounds__(512, 2) void ppo_fwd(
    const float* __restrict__ s, const float* __restrict__ sp,
    const int* __restrict__ aidx,
    const float* __restrict__ W1, const float* __restrict__ b1,
    const float* __restrict__ W2, const float* __restrict__ b2,
    const float* __restrict__ Wa, const float* __restrict__ ba,
    const float* __restrict__ Wc, const float* __restrict__ bc,
    float* __restrict__ ws_vs, float* __restrict__ ws_pia,
    float* __restrict__ ws_vsp, int nbf)
{
    __shared__ f16x8 sW1[16][64];                        // 16 KB
    __shared__ f16x8 sW2[8][64];                         //  8 KB
    __shared__ f16x8 sWh[2][64];                         //  2 KB
    __shared__ __align__(16) _Float16 hbuf[8][16 * 72];  // 18 KB
    __shared__ float hs[8][16 * 11];                     //  5.5 KB

    const int tid = threadIdx.x;
    const int pass = (blockIdx.x >= (unsigned)nbf) ? 1 : 0;
    const int rb = blockIdx.x - pass * nbf;
    const float* __restrict__ x = pass ? sp : s;

    // ---- pack weight fragments (single fp16 term) ----
    for (int idx = tid; idx < 16 * 64; idx += 512) {
        int f = idx >> 6, ll = idx & 63;
        int nt = f >> 2, kk = f & 3;
        int gg = ll >> 4, col = nt * 16 + (ll & 15);
        f16x8 v;
        #pragma unroll
        for (int j = 0; j < 8; ++j)
            v[j] = (_Float16)W1[(kk * 32 + gg * 8 + j) * H + col];
        sW1[f][ll] = v;
    }
    for (int idx = tid; idx < 8 * 64; idx += 512) {
        int f = idx >> 6, ll = idx & 63;
        int nt = f >> 1, kk = f & 1;
        int gg = ll >> 4, col = nt * 16 + (ll & 15);
        f16x8 v;
        #pragma unroll
        for (int j = 0; j < 8; ++j)
            v[j] = (_Float16)W2[(kk * 32 + gg * 8 + j) * H + col];
        sW2[f][ll] = v;
    }
    for (int idx = tid; idx < 2 * 64; idx += 512) {
        int kk = idx >> 6, ll = idx & 63;
        int gg = ll >> 4, q = ll & 15;
        f16x8 v;
        #pragma unroll
        for (int j = 0; j < 8; ++j) {
            int k = kk * 32 + gg * 8 + j;
            v[j] = (_Float16)((q == 0) ? Wc[k] : ((q <= 8) ? Wa[k * A + (q - 1)] : 0.0f));
        }
        sWh[kk][ll] = v;
    }
    __syncthreads();

    const int w = tid >> 6, l = tid & 63, g = l >> 4, n15 = l & 15;
    _Float16* hb = hbuf[w];
    float* hsw = hs[w];

    float b1r[4], b2r[4];
    #pragma unroll
    for (int nt = 0; nt < 4; ++nt) { b1r[nt] = b1[nt * 16 + n15]; b2r[nt] = b2[nt * 16 + n15]; }
    const float bhr = (n15 == 0) ? bc[0] : ((n15 <= 8) ? ba[n15 - 1] : 0.0f);

    for (int mt2 = 0; mt2 < 2; ++mt2) {
        const int t0 = rb * 512 + w * 64 + mt2 * 32;

        // ---- load x (this pass only), convert to fp16 A-frags ----
        f16x8 ax[2][4];   // [tile][kk]
        #pragma unroll
        for (int tile = 0; tile < 2; ++tile) {
            const float* row = x + (size_t)(t0 + tile * 16 + n15) * S + g * 8;
            #pragma unroll
            for (int kk = 0; kk < 4; ++kk) {
                float4 v0 = *reinterpret_cast<const float4*>(row + kk * 32);
                float4 v1 = *reinterpret_cast<const float4*>(row + kk * 32 + 4);
                f16x8 a;
                a[0] = (_Float16)v0.x; a[1] = (_Float16)v0.y;
                a[2] = (_Float16)v0.z; a[3] = (_Float16)v0.w;
                a[4] = (_Float16)v1.x; a[5] = (_Float16)v1.y;
                a[6] = (_Float16)v1.z; a[7] = (_Float16)v1.w;
                ax[tile][kk] = a;
            }
        }
        int act[2] = {0, 0};
        if (pass == 0 && l < 16) {
            act[0] = aidx[t0 + l];
            act[1] = aidx[t0 + 16 + l];
        }

        // ---- layer 1: [16x128]@[128x64], both tiles share each W-frag read ----
        f32x4 acc[2][4];
        #pragma unroll
        for (int tile = 0; tile < 2; ++tile)
            #pragma unroll
            for (int nt = 0; nt < 4; ++nt)
                acc[tile][nt] = (f32x4){b1r[nt], b1r[nt], b1r[nt], b1r[nt]};
        #pragma unroll
        for (int nt = 0; nt < 4; ++nt)
            #pragma unroll
            for (int kk = 0; kk < 4; ++kk) {
                f16x8 bw = sW1[nt * 4 + kk][l];
                acc[0][nt] = mfmaf(ax[0][kk], bw, acc[0][nt]);
                acc[1][nt] = mfmaf(ax[1][kk], bw, acc[1][nt]);
            }

        // ---- swish + LDS transpose (C layout -> A layout), per tile ----
        f16x8 a2[2][2];
        #pragma unroll
        for (int tile = 0; tile < 2; ++tile) {
            #pragma unroll
            for (int nt = 0; nt < 4; ++nt)
                #pragma unroll
                for (int rj = 0; rj < 4; ++rj)
                    hb[(g * 4 + rj) * 72 + nt * 16 + n15] =
                        (_Float16)swishf(acc[tile][nt][rj]);
            #pragma unroll
            for (int kk = 0; kk < 2; ++kk)
                a2[tile][kk] = *reinterpret_cast<f16x8*>(&hb[n15 * 72 + kk * 32 + g * 8]);
        }

        // ---- layer 2: [16x64]@[64x64] ----
        f32x4 acc2[2][4];
        #pragma unroll
        for (int tile = 0; tile < 2; ++tile)
            #pragma unroll
            for (int nt = 0; nt < 4; ++nt)
                acc2[tile][nt] = (f32x4){b2r[nt], b2r[nt], b2r[nt], b2r[nt]};
        #pragma unroll
        for (int nt = 0; nt < 4; ++nt)
            #pragma unroll
            for (int kk = 0; kk < 2; ++kk) {
                f16x8 bw = sW2[nt * 2 + kk][l];
                acc2[0][nt] = mfmaf(a2[0][kk], bw, acc2[0][nt]);
                acc2[1][nt] = mfmaf(a2[1][kk], bw, acc2[1][nt]);
            }

        // ---- transpose again -> head A-frags ----
        f16x8 a3[2][2];
        #pragma unroll
        for (int tile = 0; tile < 2; ++tile) {
            #pragma unroll
            for (int nt = 0; nt < 4; ++nt)
                #pragma unroll
                for (int rj = 0; rj < 4; ++rj)
                    hb[(g * 4 + rj) * 72 + nt * 16 + n15] =
                        (_Float16)swishf(acc2[tile][nt][rj]);
            #pragma unroll
            for (int kk = 0; kk < 2; ++kk)
                a3[tile][kk] = *reinterpret_cast<f16x8*>(&hb[n15 * 72 + kk * 32 + g * 8]);
        }

        // ---- head: [16x64]@[64x16] (col0=v, col1..8=logits) ----
        f32x4 ah[2] = {(f32x4){bhr, bhr, bhr, bhr}, (f32x4){bhr, bhr, bhr, bhr}};
        #pragma unroll
        for (int kk = 0; kk < 2; ++kk) {
            f16x8 bw = sWh[kk][l];
            ah[0] = mfmaf(a3[0][kk], bw, ah[0]);
            ah[1] = mfmaf(a3[1][kk], bw, ah[1]);
        }

        if (pass == 1) {
            // v_sp lives in col 0 = lanes with n15==0; rows g*4+rj
            #pragma unroll
            for (int tile = 0; tile < 2; ++tile)
                if (n15 == 0) {
                    #pragma unroll
                    for (int rj = 0; rj < 4; ++rj)
                        ws_vsp[t0 + tile * 16 + g * 4 + rj] = ah[tile][rj];
                }
        } else {
            // stash v + logits, softmax on lanes 0..15
            #pragma unroll
            for (int tile = 0; tile < 2; ++tile) {
                if (n15 <= 8) {
                    #pragma unroll
                    for (int rj = 0; rj < 4; ++rj)
                        hsw[(g * 4 + rj) * 11 + n15] = ah[tile][rj];
                }
                if (l < 16) {
                    float vs = hsw[l * 11 + 0];
                    float lgq[A];
                    float m = -1e30f;
                    #pragma unroll
                    for (int q = 0; q < A; ++q) {
                        lgq[q] = hsw[l * 11 + 1 + q];
                        m = fmaxf(m, lgq[q]);
                    }
                    float den = 0.f, num = 0.f;
                    #pragma unroll
                    for (int q = 0; q < A; ++q) {
                        float e = __expf(lgq[q] - m);
                        den += e;
                        num = (q == act[tile]) ? e : num;
                    }
                    int t = t0 + tile * 16 + l;
                    ws_vs[t]  = vs;
                    ws_pia[t] = num / den;
                }
            }
        }
    }
}

// ===== cooperative tail: epi + grid-wide huber mean + out write, 1 launch =====
// Each block: per-row epi for its 256 rows (out values kept in REGISTERS),
// block huber partial -> partial[blk], grid.sync(), every block redundantly
// reduces the 1024 L2-resident partials (4/thread + LDS tree), then the single
// coalesced out write with the mean folded in. Replaces ppo_epi + ppo_finish:
// one launch fewer, and out is written exactly once (no read-modify-write).
__global__ __launch_bounds__(256) void ppo_tail(
    const float* __restrict__ r, const float* __restrict__ done,
    const float* __restrict__ prob_a,
    const float* __restrict__ ws_vs, const float* __restrict__ ws_pia,
    const float* __restrict__ ws_vsp,
    float* __restrict__ out, float* __restrict__ partial,
    int Ttot, float invT)
{
    __shared__ float sred[256];
    const int tid = threadIdx.x;
    const int t = blockIdx.x * 256 + tid;
    const int nparts = gridDim.x;

    float oval = 0.f, he = 0.f;
    {
        float vs  = ws_vs[t];
        float vsp = ws_vsp[t];
        float rr  = r[t];
        float dm  = done[t];
        float ratio = ws_pia[t] / prob_a[t];

        float td_target = fmaf(GAMMA * dm, vsp, rr);
        float delta     = rr + GAMMA * vsp - vs;
        float s1 = ratio * delta;
        float rcl = fminf(fmaxf(ratio, 1.0f - EPS_CLIP), 1.0f + EPS_CLIP);
        float s2 = rcl * delta;
        oval = -fminf(s1, s2);

        float err = td_target - vs;
        float ae = fabsf(err);
        he = (ae <= 1.0f) ? (0.5f * err * err) : (ae - 0.5f);
    }

    sred[tid] = he;
    __syncthreads();
    #pragma unroll
    for (int off = 128; off > 0; off >>= 1) {
        if (tid < off) sred[tid] += sred[tid + off];
        __syncthreads();
    }
    if (tid == 0) partial[blockIdx.x] = sred[0];

    cg::this_grid().sync();

    // redundant per-block reduction of the (L2-resident) partial array
    float v = 0.f;
    for (int i = tid; i < nparts; i += 256) v += partial[i];
    sred[tid] = v;
    __syncthreads();
    #pragma unroll
    for (int off = 128; off > 0; off >>= 1) {
        if (tid < off) sred[tid] += sred[tid + off];
        __syncthreads();
    }
    out[t] = oval + sred[0] * invT;
}

extern "C" void kernel_launch(void* const* d_in, const int* in_sizes, int n_in,
                              void* d_out, int out_size, void* d_ws, size_t ws_size,
                              hipStream_t stream)
{
    const float* s      = (const float*)d_in[0];
    const float* sp     = (const float*)d_in[1];
    const float* r      = (const float*)d_in[2];
    const float* done   = (const float*)d_in[3];
    const float* prob_a = (const float*)d_in[4];
    const int*   a      = (const int*)d_in[5];
    const float* W1     = (const float*)d_in[6];
    const float* b1     = (const float*)d_in[7];
    const float* W2     = (const float*)d_in[8];
    const float* b2     = (const float*)d_in[9];
    const float* Wa     = (const float*)d_in[10];
    const float* ba     = (const float*)d_in[11];
    const float* Wc     = (const float*)d_in[12];
    const float* bc     = (const float*)d_in[13];

    float* out = (float*)d_out;
    float* ws  = (float*)d_ws;

    const int Ttot = in_sizes[0] / S;              // 262144
    const int nbf  = Ttot / 512;                   // 512 fwd row-blocks (512 rows each)
    const int nbe  = Ttot / 256;                   // 1024 tail blocks

    float* ws_vs  = ws;
    float* ws_pia = ws + Ttot;
    float* ws_vsp = ws + 2 * (size_t)Ttot;
    float* partial = ws + 3 * (size_t)Ttot;        // nbe floats

    ppo_fwd<<<2 * nbf, 512, 0, stream>>>(s, sp, a, W1, b1, W2, b2, Wa, ba, Wc, bc,
                                         ws_vs, ws_pia, ws_vsp, nbf);

    float invT = 1.0f / (float)Ttot;
    void* args[] = {(void*)&r, (void*)&done, (void*)&prob_a,
                    (void*)&ws_vs, (void*)&ws_pia, (void*)&ws_vsp,
                    (void*)&out, (void*)&partial, (void*)&Ttot, (void*)&invT};
    hipLaunchCooperativeKernel(reinterpret_cast<void*>(ppo_tail),
                               dim3(nbe), dim3(256), args, 0, stream);
}

// Round 9
// 62.010 us; speedup vs baseline: 1.8251x; 1.8251x over previous
//
#include <hip/hip_runtime.h>
#include <cstddef>
#include <cstdint>

typedef __attribute__((ext_vector_type(8))) _Float16 f16x8;
typedef __attribute__((ext_vector_type(4))) float f32x4;

constexpr int S = 128;
constexpr int H = 64;
constexpr int A = 8;
constexpr float GAMMA = 0.98f;
constexpr float EPS_CLIP = 0.1f;

__device__ __forceinline__ float swishf(float x) {
    return x * __builtin_amdgcn_rcpf(1.0f + __expf(-x));
}
__device__ __forceinline__ f32x4 mfmaf(f16x8 a, f16x8 b, f32x4 c) {
    return __builtin_amdgcn_mfma_f32_16x16x32_f16(a, b, c, 0, 0, 0);
}

// ===== r4 fwd, byte-identical (best measured: bench 62.7 us) =====
// Grid = 2*nbf blocks of 512 threads (8 waves). Blocks [0,nbf): pass 0 over s
// (writes v_s and pi_a). Blocks [nbf,2nbf): pass 1 over s' (writes v_sp).
// 512-thread blocks: weights staged once per 512 rows; LDS 49.5 KB.
// __launch_bounds__(512,2): no register strangling (r3's (512,6) spilled).
// Each wave owns 64 rows as 2 double-tiles of 32 rows; both 16-row tiles of a
// double-tile share every weight-fragment ds_read.
// A-frag (16x32 f16): lane l holds A[l&15][(l>>4)*8 + j].
// B-frag: lane l holds B[(l>>4)*8 + j][l&15].  C/D: col=lane&15, row=(lane>>4)*4+reg.
__global__ __launch_bounds__(512, 2) void ppo_fwd(
    const float* __restrict__ s, const float* __restrict__ sp,
    const int* __restrict__ aidx,
    const float* __restrict__ W1, const float* __restrict__ b1,
    const float* __restrict__ W2, const float* __restrict__ b2,
    const float* __restrict__ Wa, const float* __restrict__ ba,
    const float* __restrict__ Wc, const float* __restrict__ bc,
    float* __restrict__ ws_vs, float* __restrict__ ws_pia,
    float* __restrict__ ws_vsp, int nbf)
{
    __shared__ f16x8 sW1[16][64];                        // 16 KB
    __shared__ f16x8 sW2[8][64];                         //  8 KB
    __shared__ f16x8 sWh[2][64];                         //  2 KB
    __shared__ __align__(16) _Float16 hbuf[8][16 * 72];  // 18 KB
    __shared__ float hs[8][16 * 11];                     //  5.5 KB

    const int tid = threadIdx.x;
    const int pass = (blockIdx.x >= (unsigned)nbf) ? 1 : 0;
    const int rb = blockIdx.x - pass * nbf;
    const float* __restrict__ x = pass ? sp : s;

    // ---- pack weight fragments (single fp16 term) ----
    for (int idx = tid; idx < 16 * 64; idx += 512) {
        int f = idx >> 6, ll = idx & 63;
        int nt = f >> 2, kk = f & 3;
        int gg = ll >> 4, col = nt * 16 + (ll & 15);
        f16x8 v;
        #pragma unroll
        for (int j = 0; j < 8; ++j)
            v[j] = (_Float16)W1[(kk * 32 + gg * 8 + j) * H + col];
        sW1[f][ll] = v;
    }
    for (int idx = tid; idx < 8 * 64; idx += 512) {
        int f = idx >> 6, ll = idx & 63;
        int nt = f >> 1, kk = f & 1;
        int gg = ll >> 4, col = nt * 16 + (ll & 15);
        f16x8 v;
        #pragma unroll
        for (int j = 0; j < 8; ++j)
            v[j] = (_Float16)W2[(kk * 32 + gg * 8 + j) * H + col];
        sW2[f][ll] = v;
    }
    for (int idx = tid; idx < 2 * 64; idx += 512) {
        int kk = idx >> 6, ll = idx & 63;
        int gg = ll >> 4, q = ll & 15;
        f16x8 v;
        #pragma unroll
        for (int j = 0; j < 8; ++j) {
            int k = kk * 32 + gg * 8 + j;
            v[j] = (_Float16)((q == 0) ? Wc[k] : ((q <= 8) ? Wa[k * A + (q - 1)] : 0.0f));
        }
        sWh[kk][ll] = v;
    }
    __syncthreads();

    const int w = tid >> 6, l = tid & 63, g = l >> 4, n15 = l & 15;
    _Float16* hb = hbuf[w];
    float* hsw = hs[w];

    float b1r[4], b2r[4];
    #pragma unroll
    for (int nt = 0; nt < 4; ++nt) { b1r[nt] = b1[nt * 16 + n15]; b2r[nt] = b2[nt * 16 + n15]; }
    const float bhr = (n15 == 0) ? bc[0] : ((n15 <= 8) ? ba[n15 - 1] : 0.0f);

    for (int mt2 = 0; mt2 < 2; ++mt2) {
        const int t0 = rb * 512 + w * 64 + mt2 * 32;

        // ---- load x (this pass only), convert to fp16 A-frags ----
        f16x8 ax[2][4];   // [tile][kk]
        #pragma unroll
        for (int tile = 0; tile < 2; ++tile) {
            const float* row = x + (size_t)(t0 + tile * 16 + n15) * S + g * 8;
            #pragma unroll
            for (int kk = 0; kk < 4; ++kk) {
                float4 v0 = *reinterpret_cast<const float4*>(row + kk * 32);
                float4 v1 = *reinterpret_cast<const float4*>(row + kk * 32 + 4);
                f16x8 a;
                a[0] = (_Float16)v0.x; a[1] = (_Float16)v0.y;
                a[2] = (_Float16)v0.z; a[3] = (_Float16)v0.w;
                a[4] = (_Float16)v1.x; a[5] = (_Float16)v1.y;
                a[6] = (_Float16)v1.z; a[7] = (_Float16)v1.w;
                ax[tile][kk] = a;
            }
        }
        int act[2] = {0, 0};
        if (pass == 0 && l < 16) {
            act[0] = aidx[t0 + l];
            act[1] = aidx[t0 + 16 + l];
        }

        // ---- layer 1: [16x128]@[128x64], both tiles share each W-frag read ----
        f32x4 acc[2][4];
        #pragma unroll
        for (int tile = 0; tile < 2; ++tile)
            #pragma unroll
            for (int nt = 0; nt < 4; ++nt)
                acc[tile][nt] = (f32x4){b1r[nt], b1r[nt], b1r[nt], b1r[nt]};
        #pragma unroll
        for (int nt = 0; nt < 4; ++nt)
            #pragma unroll
            for (int kk = 0; kk < 4; ++kk) {
                f16x8 bw = sW1[nt * 4 + kk][l];
                acc[0][nt] = mfmaf(ax[0][kk], bw, acc[0][nt]);
                acc[1][nt] = mfmaf(ax[1][kk], bw, acc[1][nt]);
            }

        // ---- swish + LDS transpose (C layout -> A layout), per tile ----
        f16x8 a2[2][2];
        #pragma unroll
        for (int tile = 0; tile < 2; ++tile) {
            #pragma unroll
            for (int nt = 0; nt < 4; ++nt)
                #pragma unroll
                for (int rj = 0; rj < 4; ++rj)
                    hb[(g * 4 + rj) * 72 + nt * 16 + n15] =
                        (_Float16)swishf(acc[tile][nt][rj]);
            #pragma unroll
            for (int kk = 0; kk < 2; ++kk)
                a2[tile][kk] = *reinterpret_cast<f16x8*>(&hb[n15 * 72 + kk * 32 + g * 8]);
        }

        // ---- layer 2: [16x64]@[64x64] ----
        f32x4 acc2[2][4];
        #pragma unroll
        for (int tile = 0; tile < 2; ++tile)
            #pragma unroll
            for (int nt = 0; nt < 4; ++nt)
                acc2[tile][nt] = (f32x4){b2r[nt], b2r[nt], b2r[nt], b2r[nt]};
        #pragma unroll
        for (int nt = 0; nt < 4; ++nt)
            #pragma unroll
            for (int kk = 0; kk < 2; ++kk) {
                f16x8 bw = sW2[nt * 2 + kk][l];
                acc2[0][nt] = mfmaf(a2[0][kk], bw, acc2[0][nt]);
                acc2[1][nt] = mfmaf(a2[1][kk], bw, acc2[1][nt]);
            }

        // ---- transpose again -> head A-frags ----
        f16x8 a3[2][2];
        #pragma unroll
        for (int tile = 0; tile < 2; ++tile) {
            #pragma unroll
            for (int nt = 0; nt < 4; ++nt)
                #pragma unroll
                for (int rj = 0; rj < 4; ++rj)
                    hb[(g * 4 + rj) * 72 + nt * 16 + n15] =
                        (_Float16)swishf(acc2[tile][nt][rj]);
            #pragma unroll
            for (int kk = 0; kk < 2; ++kk)
                a3[tile][kk] = *reinterpret_cast<f16x8*>(&hb[n15 * 72 + kk * 32 + g * 8]);
        }

        // ---- head: [16x64]@[64x16] (col0=v, col1..8=logits) ----
        f32x4 ah[2] = {(f32x4){bhr, bhr, bhr, bhr}, (f32x4){bhr, bhr, bhr, bhr}};
        #pragma unroll
        for (int kk = 0; kk < 2; ++kk) {
            f16x8 bw = sWh[kk][l];
            ah[0] = mfmaf(a3[0][kk], bw, ah[0]);
            ah[1] = mfmaf(a3[1][kk], bw, ah[1]);
        }

        if (pass == 1) {
            // v_sp lives in col 0 = lanes with n15==0; rows g*4+rj
            #pragma unroll
            for (int tile = 0; tile < 2; ++tile)
                if (n15 == 0) {
                    #pragma unroll
                    for (int rj = 0; rj < 4; ++rj)
                        ws_vsp[t0 + tile * 16 + g * 4 + rj] = ah[tile][rj];
                }
        } else {
            // stash v + logits, softmax on lanes 0..15
            #pragma unroll
            for (int tile = 0; tile < 2; ++tile) {
                if (n15 <= 8) {
                    #pragma unroll
                    for (int rj = 0; rj < 4; ++rj)
                        hsw[(g * 4 + rj) * 11 + n15] = ah[tile][rj];
                }
                if (l < 16) {
                    float vs = hsw[l * 11 + 0];
                    float lgq[A];
                    float m = -1e30f;
                    #pragma unroll
                    for (int q = 0; q < A; ++q) {
                        lgq[q] = hsw[l * 11 + 1 + q];
                        m = fmaxf(m, lgq[q]);
                    }
                    float den = 0.f, num = 0.f;
                    #pragma unroll
                    for (int q = 0; q < A; ++q) {
                        float e = __expf(lgq[q] - m);
                        den += e;
                        num = (q == act[tile]) ? e : num;
                    }
                    int t = t0 + tile * 16 + l;
                    ws_vs[t]  = vs;
                    ws_pia[t] = num / den;
                }
            }
        }
    }
}

// Per-row epilogue: out[t] = -min(surr1,surr2); huber partials per block.
__global__ __launch_bounds__(256) void ppo_epi(
    const float* __restrict__ r, const float* __restrict__ done,
    const float* __restrict__ prob_a,
    const float* __restrict__ ws_vs, const float* __restrict__ ws_pia,
    const float* __restrict__ ws_vsp,
    float* __restrict__ out, float* __restrict__ partial, int Ttot)
{
    __shared__ float sred[256];
    const int tid = threadIdx.x;
    const int t = blockIdx.x * 256 + tid;

    float he = 0.f;
    if (t < Ttot) {
        float vs  = ws_vs[t];
        float vsp = ws_vsp[t];
        float rr  = r[t];
        float dm  = done[t];
        float ratio = ws_pia[t] / prob_a[t];

        float td_target = fmaf(GAMMA * dm, vsp, rr);
        float delta     = rr + GAMMA * vsp - vs;
        float s1 = ratio * delta;
        float rcl = fminf(fmaxf(ratio, 1.0f - EPS_CLIP), 1.0f + EPS_CLIP);
        float s2 = rcl * delta;
        out[t] = -fminf(s1, s2);

        float err = td_target - vs;
        float ae = fabsf(err);
        he = (ae <= 1.0f) ? (0.5f * err * err) : (ae - 0.5f);
    }

    sred[tid] = he;
    __syncthreads();
    #pragma unroll
    for (int off = 128; off > 0; off >>= 1) {
        if (tid < off) sred[tid] += sred[tid + off];
        __syncthreads();
    }
    if (tid == 0) partial[blockIdx.x] = sred[0];
}

// Every block redundantly reduces the (L2-resident) partial array to the huber
// mean, then adds it to its own slice of out. Replaces the serial single-block
// ppo_reduce + ppo_add pair: one fewer launch, no serial 1-block kernel.
__global__ __launch_bounds__(256) void ppo_finish(
    const float* __restrict__ partial, int nparts, float invT,
    float4* __restrict__ out4, int n4)
{
    __shared__ float sred[256];
    const int tid = threadIdx.x;
    float v = 0.f;
    for (int i = tid; i < nparts; i += 256) v += partial[i];
    sred[tid] = v;
    __syncthreads();
    #pragma unroll
    for (int off = 128; off > 0; off >>= 1) {
        if (tid < off) sred[tid] += sred[tid + off];
        __syncthreads();
    }
    const float m = sred[0] * invT;
    const int i = blockIdx.x * 256 + tid;
    if (i < n4) {
        float4 o = out4[i];
        o.x += m; o.y += m; o.z += m; o.w += m;
        out4[i] = o;
    }
}

extern "C" void kernel_launch(void* const* d_in, const int* in_sizes, int n_in,
                              void* d_out, int out_size, void* d_ws, size_t ws_size,
                              hipStream_t stream)
{
    const float* s      = (const float*)d_in[0];
    const float* sp     = (const float*)d_in[1];
    const float* r      = (const float*)d_in[2];
    const float* done   = (const float*)d_in[3];
    const float* prob_a = (const float*)d_in[4];
    const int*   a      = (const int*)d_in[5];
    const float* W1     = (const float*)d_in[6];
    const float* b1     = (const float*)d_in[7];
    const float* W2     = (const float*)d_in[8];
    const float* b2     = (const float*)d_in[9];
    const float* Wa     = (const float*)d_in[10];
    const float* ba     = (const float*)d_in[11];
    const float* Wc     = (const float*)d_in[12];
    const float* bc     = (const float*)d_in[13];

    float* out = (float*)d_out;
    float* ws  = (float*)d_ws;

    const int Ttot = in_sizes[0] / S;              // 262144
    const int nbf  = Ttot / 512;                   // 512 fwd row-blocks (512 rows each)
    const int nbe  = Ttot / 256;                   // 1024 epi blocks

    float* ws_vs  = ws;
    float* ws_pia = ws + Ttot;
    float* ws_vsp = ws + 2 * (size_t)Ttot;
    float* partial = ws + 3 * (size_t)Ttot;        // nbe floats

    ppo_fwd<<<2 * nbf, 512, 0, stream>>>(s, sp, a, W1, b1, W2, b2, Wa, ba, Wc, bc,
                                         ws_vs, ws_pia, ws_vsp, nbf);
    ppo_epi<<<nbe, 256, 0, stream>>>(r, done, prob_a, ws_vs, ws_pia, ws_vsp,
                                     out, partial, Ttot);

    const int n4 = Ttot / 4;
    ppo_finish<<<(n4 + 255) / 256, 256, 0, stream>>>(partial, nbe,
                                                     1.0f / (float)Ttot,
                                                     (float4*)out, n4);
}